// Round 3
// baseline (1629.026 us; speedup 1.0000x reference)
//
#include <hip/hip_runtime.h>
#include <math.h>

#define NVOX 120000
#define CDIM 128
#define NWIN 5000
#define HWPIX 102400

typedef __attribute__((ext_vector_type(8))) short short8;
typedef __attribute__((ext_vector_type(4))) float f32x4;

__device__ __forceinline__ unsigned short f2bf(float f) {
  unsigned u = __float_as_uint(f);
  return (unsigned short)((u + 0x7FFFu + ((u >> 16) & 1u)) >> 16);
}
__device__ __forceinline__ unsigned pack2(float a, float b) {
  return (unsigned)f2bf(a) | ((unsigned)f2bf(b) << 16);
}
__device__ __forceinline__ void unpack2(unsigned u, float& a, float& b) {
  a = __uint_as_float(u << 16);
  b = __uint_as_float(u & 0xFFFF0000u);
}

// ============================================================================
// MFMA core helper. Block=256 (4 waves). Wave tile: M=16*MT x N=64.
// LDS pitch 136 bf16 (272B -> 2-way bank aliasing, free).
// A-frag: A[m=lane&15][k=quad*8+j]; B-frag: W[n=lane&15][k] (W row-major [N][K]).
// C/D: col=lane&15, row=quad*4+reg.
// ============================================================================
template <int MT>
__device__ __forceinline__ void mma_k128(const short* __restrict__ As,
                                         const short* __restrict__ Ws,
                                         int aoff, int astride, int boff,
                                         f32x4 acc[MT][4]) {
#pragma unroll
  for (int kc = 0; kc < 4; ++kc) {
    short8 a[MT];
#pragma unroll
    for (int mt = 0; mt < MT; ++mt)
      a[mt] = *(const short8*)(As + aoff + mt * astride + kc * 32);
#pragma unroll
    for (int nt = 0; nt < 4; ++nt) {
      short8 b = *(const short8*)(Ws + boff + nt * 136 * 16 + kc * 32);
#pragma unroll
      for (int mt = 0; mt < MT; ++mt)
        acc[mt][nt] = __builtin_amdgcn_mfma_f32_16x16x32_bf16(a[mt], b, acc[mt][nt], 0, 0, 0);
    }
  }
}

// ---------------------------------------------------------------------------
__global__ __launch_bounds__(256) void cvt_kernel(const float* __restrict__ src,
                                                  unsigned short* __restrict__ dst, int n4) {
  int i = blockIdx.x * 256 + threadIdx.x;
  if (i >= n4) return;
  float4 v = ((const float4*)src)[i];
  uint2 o; o.x = pack2(v.x, v.y); o.y = pack2(v.z, v.w);
  ((uint2*)dst)[i] = o;
}

__global__ __launch_bounds__(256) void cvtT_kernel(const float* __restrict__ w,
                                                   unsigned short* __restrict__ wT) {
  int idx = blockIdx.x * 256 + threadIdx.x;
  if (idx >= 2 * 9 * 128 * 128) return;
  int ci = idx & 127;
  int co = (idx >> 7) & 127;
  int tap = (idx >> 14) % 9;
  int conv = idx / (9 * 16384);
  wT[idx] = f2bf(w[((size_t)(conv * 128 + co) * 128 + ci) * 9 + tap]);
}

// ---------------------------------------------------------------------------
// Fused QKV: one dispatch. A=(x+pos) staged once, used for q and k; A=x
// restaged for v. Ws staged per section; epilogue via Ybf aliasing Ws region.
__global__ __launch_bounds__(256) void qkv_kernel(
    const unsigned short* __restrict__ x, const float* __restrict__ pos,
    const int* __restrict__ ind, const unsigned short* __restrict__ ipwB,
    const float* __restrict__ ipb, unsigned short* __restrict__ qb,
    unsigned short* __restrict__ kb, unsigned short* __restrict__ vb) {
  __shared__ __align__(16) char ldsraw[52480];
  short* As = (short*)ldsraw;              // [64][136]
  short* Ws = (short*)(ldsraw + 17408);    // [128][136]; aliased by Ybf [64][136]
  int* slots = (int*)(ldsraw + 52224);     // [64]
  const int t = threadIdx.x;
  const int lane = t & 63, wv = t >> 6;
  const int l15 = lane & 15, quad = lane >> 4;
  const int rbase = 32 * (wv >> 1), cbase = 64 * (wv & 1);
  const int mbase = blockIdx.x * 64;

  if (t < 64) {
    int s = ind[mbase + t];
    slots[t] = (s / 36) * 24 + (s % 36);
  }
  // stage A = x + pos
  for (int fi = t; fi < 1024; fi += 256) {
    int row = fi >> 4, c8 = fi & 15;
    int vox = mbase + row;
    uint4 xv = ((const uint4*)x)[(size_t)vox * 16 + c8];
    int s = ind[vox];
    const float4* pp = (const float4*)(pos + (size_t)s * 128 + c8 * 8);
    float4 p0 = pp[0], p1 = pp[1];
    float f0, f1, f2, f3, f4, f5, f6, f7;
    unpack2(xv.x, f0, f1); unpack2(xv.y, f2, f3);
    unpack2(xv.z, f4, f5); unpack2(xv.w, f6, f7);
    xv.x = pack2(f0 + p0.x, f1 + p0.y); xv.y = pack2(f2 + p0.z, f3 + p0.w);
    xv.z = pack2(f4 + p1.x, f5 + p1.y); xv.w = pack2(f6 + p1.z, f7 + p1.w);
    *(uint4*)&As[row * 136 + c8 * 8] = xv;
  }

  for (int sec = 0; sec < 3; ++sec) {
    if (sec == 2) {  // restage A = x (raw) for v-projection
      for (int fi = t; fi < 1024; fi += 256) {
        int row = fi >> 4, c8 = fi & 15;
        *(uint4*)&As[row * 136 + c8 * 8] =
            ((const uint4*)x)[(size_t)(mbase + row) * 16 + c8];
      }
    }
    for (int fi = t; fi < 2048; fi += 256) {
      int row = fi >> 4, c8 = fi & 15;
      ((uint4*)&Ws[row * 136])[c8] =
          ((const uint4*)(ipwB + (size_t)(sec * 128 + row) * 128))[c8];
    }
    __syncthreads();
    f32x4 acc[2][4];
#pragma unroll
    for (int m = 0; m < 2; ++m)
#pragma unroll
      for (int n = 0; n < 4; ++n) acc[m][n] = (f32x4){0.f, 0.f, 0.f, 0.f};
    mma_k128<2>(As, Ws, (rbase + l15) * 136 + quad * 8, 16 * 136,
                (cbase + l15) * 136 + quad * 8, acc);
    __syncthreads();
    short* Ybf = Ws;  // alias
#pragma unroll
    for (int nt = 0; nt < 4; ++nt) {
      int col = cbase + nt * 16 + l15;
      float bias = ipb[sec * 128 + col];
#pragma unroll
      for (int mt = 0; mt < 2; ++mt)
#pragma unroll
        for (int r = 0; r < 4; ++r)
          Ybf[(rbase + mt * 16 + quad * 4 + r) * 136 + col] =
              (short)f2bf(acc[mt][nt][r] + bias);
    }
    __syncthreads();
    unsigned short* dst = (sec == 0) ? qb : ((sec == 1) ? kb : vb);
    for (int fi = t; fi < 1024; fi += 256) {
      int row = fi >> 4, c8 = fi & 15;
      ((uint4*)dst)[(size_t)slots[row] * 16 + c8] = ((const uint4*)&Ybf[row * 136])[c8];
    }
    __syncthreads();  // protect Ws/As restage next iteration
  }
}

// ---------------------------------------------------------------------------
// Attention: one block per window; threads t<192 each own one (head, q-row).
// Scores + softmax entirely in registers; LDS reads broadcast across lanes
// sharing a head.
__global__ __launch_bounds__(256) void attn_kernel(
    unsigned short* __restrict__ qb, const unsigned short* __restrict__ kb,
    const unsigned short* __restrict__ vb) {
  __shared__ float lds[9504];  // Qs/Ks/Vs [24][132] each
  float* Qs = lds;
  float* Ks = lds + 3168;
  float* Vs = lds + 6336;
  const int t = threadIdx.x;
  const size_t base = (size_t)blockIdx.x * 3072;
  for (int fi = t; fi < 1152; fi += 256) {
    int arr = fi / 384, rem = fi - arr * 384;
    int row = rem >> 4, c8 = rem & 15;
    const unsigned short* src = arr == 0 ? qb : (arr == 1 ? kb : vb);
    uint4 raw = ((const uint4*)(src + base))[row * 16 + c8];
    float* dl = lds + arr * 3168 + row * 132 + c8 * 8;
    unpack2(raw.x, dl[0], dl[1]); unpack2(raw.y, dl[2], dl[3]);
    unpack2(raw.z, dl[4], dl[5]); unpack2(raw.w, dl[6], dl[7]);
  }
  __syncthreads();
  if (t < 192) {
    int h = t / 24, q = t - h * 24;
    const float4* qp = (const float4*)&Qs[q * 132 + h * 16];
    float4 q0 = qp[0], q1 = qp[1], q2 = qp[2], q3 = qp[3];
    float sc[24];
#pragma unroll
    for (int k = 0; k < 24; ++k) {
      const float4* kp = (const float4*)&Ks[k * 132 + h * 16];
      float4 k0 = kp[0], k1 = kp[1], k2 = kp[2], k3 = kp[3];
      float s = 0.f;
      s = fmaf(q0.x, k0.x, s); s = fmaf(q0.y, k0.y, s);
      s = fmaf(q0.z, k0.z, s); s = fmaf(q0.w, k0.w, s);
      s = fmaf(q1.x, k1.x, s); s = fmaf(q1.y, k1.y, s);
      s = fmaf(q1.z, k1.z, s); s = fmaf(q1.w, k1.w, s);
      s = fmaf(q2.x, k2.x, s); s = fmaf(q2.y, k2.y, s);
      s = fmaf(q2.z, k2.z, s); s = fmaf(q2.w, k2.w, s);
      s = fmaf(q3.x, k3.x, s); s = fmaf(q3.y, k3.y, s);
      s = fmaf(q3.z, k3.z, s); s = fmaf(q3.w, k3.w, s);
      sc[k] = s * 0.25f;
    }
    float m = sc[0];
#pragma unroll
    for (int k = 1; k < 24; ++k) m = fmaxf(m, sc[k]);
    float sum = 0.f;
#pragma unroll
    for (int k = 0; k < 24; ++k) { sc[k] = __expf(sc[k] - m); sum += sc[k]; }
    float inv = 1.f / sum;
    float4 o0 = {0,0,0,0}, o1 = o0, o2 = o0, o3 = o0;
#pragma unroll
    for (int k = 0; k < 24; ++k) {
      float p = sc[k] * inv;
      const float4* vp = (const float4*)&Vs[k * 132 + h * 16];
      float4 v0 = vp[0], v1 = vp[1], v2 = vp[2], v3 = vp[3];
      o0.x = fmaf(p, v0.x, o0.x); o0.y = fmaf(p, v0.y, o0.y);
      o0.z = fmaf(p, v0.z, o0.z); o0.w = fmaf(p, v0.w, o0.w);
      o1.x = fmaf(p, v1.x, o1.x); o1.y = fmaf(p, v1.y, o1.y);
      o1.z = fmaf(p, v1.z, o1.z); o1.w = fmaf(p, v1.w, o1.w);
      o2.x = fmaf(p, v2.x, o2.x); o2.y = fmaf(p, v2.y, o2.y);
      o2.z = fmaf(p, v2.z, o2.z); o2.w = fmaf(p, v2.w, o2.w);
      o3.x = fmaf(p, v3.x, o3.x); o3.y = fmaf(p, v3.y, o3.y);
      o3.z = fmaf(p, v3.z, o3.z); o3.w = fmaf(p, v3.w, o3.w);
    }
    uint4 lo, hi;
    lo.x = pack2(o0.x, o0.y); lo.y = pack2(o0.z, o0.w);
    lo.z = pack2(o1.x, o1.y); lo.w = pack2(o1.z, o1.w);
    hi.x = pack2(o2.x, o2.y); hi.y = pack2(o2.z, o2.w);
    hi.z = pack2(o3.x, o3.y); hi.w = pack2(o3.z, o3.w);
    ((uint4*)(qb + base))[q * 16 + h * 2] = lo;
    ((uint4*)(qb + base))[q * 16 + h * 2 + 1] = hi;
  }
}

// ---------------------------------------------------------------------------
__global__ __launch_bounds__(256) void outln_kernel(
    const unsigned short* __restrict__ o, const int* __restrict__ ind,
    const unsigned short* __restrict__ opwB, const float* __restrict__ opb,
    const unsigned short* __restrict__ xres, const float* __restrict__ lnw,
    const float* __restrict__ lnb, unsigned short* __restrict__ hout) {
  __shared__ __align__(16) char ldsraw[52224];
  short* As = (short*)ldsraw;
  short* Ws = (short*)(ldsraw + 17408);
  const int t = threadIdx.x;
  const int lane = t & 63, wv = t >> 6;
  const int l15 = lane & 15, quad = lane >> 4;
  const int rbase = 32 * (wv >> 1), cbase = 64 * (wv & 1);
  const int mbase = blockIdx.x * 64;
  f32x4 acc[2][4];
#pragma unroll
  for (int m = 0; m < 2; ++m)
#pragma unroll
    for (int n = 0; n < 4; ++n) acc[m][n] = (f32x4){0.f, 0.f, 0.f, 0.f};

  for (int fi = t; fi < 1024; fi += 256) {
    int row = fi >> 4, c8 = fi & 15;
    int s = ind[mbase + row];
    int slot = (s / 36) * 24 + (s % 36);
    *(uint4*)&As[row * 136 + c8 * 8] = ((const uint4*)o)[(size_t)slot * 16 + c8];
  }
  for (int fi = t; fi < 2048; fi += 256) {
    int row = fi >> 4, c8 = fi & 15;
    ((uint4*)&Ws[row * 136])[c8] = ((const uint4*)(opwB + (size_t)row * 128))[c8];
  }
  __syncthreads();
  mma_k128<2>(As, Ws, (rbase + l15) * 136 + quad * 8, 16 * 136,
              (cbase + l15) * 136 + quad * 8, acc);
  __syncthreads();

  float* Yf = (float*)ldsraw;               // [64][132]
  float* p1 = (float*)(ldsraw + 33792);
  float* p2 = (float*)(ldsraw + 34816);
  float* Ms = (float*)(ldsraw + 35840);
  float* Rs = (float*)(ldsraw + 36096);
#pragma unroll
  for (int nt = 0; nt < 4; ++nt) {
    int col = cbase + nt * 16 + l15;
    float bias = opb[col];
#pragma unroll
    for (int mt = 0; mt < 2; ++mt)
#pragma unroll
      for (int r = 0; r < 4; ++r)
        Yf[(rbase + mt * 16 + quad * 4 + r) * 132 + col] = acc[mt][nt][r] + bias;
  }
  __syncthreads();
  for (int fi = t; fi < 1024; fi += 256) {
    int row = fi >> 4, c8 = fi & 15;
    uint4 xv = ((const uint4*)xres)[(size_t)(mbase + row) * 16 + c8];
    float* yp = &Yf[row * 132 + c8 * 8];
    float a, b;
    unpack2(xv.x, a, b); yp[0] += a; yp[1] += b;
    unpack2(xv.y, a, b); yp[2] += a; yp[3] += b;
    unpack2(xv.z, a, b); yp[4] += a; yp[5] += b;
    unpack2(xv.w, a, b); yp[6] += a; yp[7] += b;
  }
  __syncthreads();
  {
    int r = t & 63, g = t >> 6;
    float s = 0.f, s2 = 0.f;
    for (int c = g * 32; c < g * 32 + 32; ++c) { float v = Yf[r * 132 + c]; s += v; s2 += v * v; }
    p1[g * 64 + r] = s; p2[g * 64 + r] = s2;
  }
  __syncthreads();
  if (t < 64) {
    float s = p1[t] + p1[64 + t] + p1[128 + t] + p1[192 + t];
    float s2 = p2[t] + p2[64 + t] + p2[128 + t] + p2[192 + t];
    float m = s * (1.f / 128.f);
    float var = s2 * (1.f / 128.f) - m * m;
    Ms[t] = m; Rs[t] = rsqrtf(var + 1e-5f);
  }
  __syncthreads();
  for (int fi = t; fi < 1024; fi += 256) {
    int row = fi >> 4, c8 = fi & 15;
    float m = Ms[row], rr = Rs[row];
    const float* yp = &Yf[row * 132 + c8 * 8];
    uint4 ov;
    float v0, v1;
#define LNPAIR(J, FLD) \
    v0 = (yp[2*J] - m) * rr * lnw[c8*8+2*J] + lnb[c8*8+2*J]; \
    v1 = (yp[2*J+1] - m) * rr * lnw[c8*8+2*J+1] + lnb[c8*8+2*J+1]; \
    ov.FLD = pack2(v0, v1);
    LNPAIR(0, x) LNPAIR(1, y) LNPAIR(2, z) LNPAIR(3, w)
#undef LNPAIR
    ((uint4*)hout)[(size_t)(mbase + row) * 16 + c8] = ov;
  }
}

// ---------------------------------------------------------------------------
// FFN1 fused: stage h once, loop both 128-col halves of DFF=256.
__global__ __launch_bounds__(256) void ffn1_kernel(
    const unsigned short* __restrict__ h, const unsigned short* __restrict__ w1B,
    const float* __restrict__ b1, unsigned short* __restrict__ ff) {
  __shared__ __align__(16) char ldsraw[52224];
  short* As = (short*)ldsraw;
  short* Ws = (short*)(ldsraw + 17408);
  const int t = threadIdx.x;
  const int lane = t & 63, wv = t >> 6;
  const int l15 = lane & 15, quad = lane >> 4;
  const int rbase = 32 * (wv >> 1), cbase = 64 * (wv & 1);
  const int mbase = blockIdx.x * 64;

  for (int fi = t; fi < 1024; fi += 256) {
    int row = fi >> 4, c8 = fi & 15;
    *(uint4*)&As[row * 136 + c8 * 8] = ((const uint4*)h)[(size_t)(mbase + row) * 16 + c8];
  }
  for (int by = 0; by < 2; ++by) {
    for (int fi = t; fi < 2048; fi += 256) {
      int row = fi >> 4, c8 = fi & 15;
      ((uint4*)&Ws[row * 136])[c8] =
          ((const uint4*)(w1B + (size_t)(by * 128 + row) * 128))[c8];
    }
    __syncthreads();
    f32x4 acc[2][4];
#pragma unroll
    for (int m = 0; m < 2; ++m)
#pragma unroll
      for (int n = 0; n < 4; ++n) acc[m][n] = (f32x4){0.f, 0.f, 0.f, 0.f};
    mma_k128<2>(As, Ws, (rbase + l15) * 136 + quad * 8, 16 * 136,
                (cbase + l15) * 136 + quad * 8, acc);
    __syncthreads();
    short* Ybf = Ws;  // alias
#pragma unroll
    for (int nt = 0; nt < 4; ++nt) {
      int col = cbase + nt * 16 + l15;
      float bias = b1[by * 128 + col];
#pragma unroll
      for (int mt = 0; mt < 2; ++mt)
#pragma unroll
        for (int r = 0; r < 4; ++r) {
          float v = acc[mt][nt][r] + bias;
          float g = 0.5f * v * (1.f + erff(v * 0.70710678f));
          Ybf[(rbase + mt * 16 + quad * 4 + r) * 136 + col] = (short)f2bf(g);
        }
    }
    __syncthreads();
    for (int fi = t; fi < 1024; fi += 256) {
      int row = fi >> 4, c8 = fi & 15;
      ((uint4*)ff)[(size_t)(mbase + row) * 32 + by * 16 + c8] =
          ((const uint4*)&Ybf[row * 136])[c8];
    }
    __syncthreads();
  }
}

// ---------------------------------------------------------------------------
__global__ __launch_bounds__(256) void ffn2_kernel(
    const unsigned short* __restrict__ ff, const unsigned short* __restrict__ w2B,
    const float* __restrict__ b2, const unsigned short* __restrict__ hres,
    const float* __restrict__ lnw, const float* __restrict__ lnb,
    unsigned short* __restrict__ xout) {
  __shared__ __align__(16) char ldsraw[52224];
  short* As = (short*)ldsraw;
  short* Ws = (short*)(ldsraw + 17408);
  const int t = threadIdx.x;
  const int lane = t & 63, wv = t >> 6;
  const int l15 = lane & 15, quad = lane >> 4;
  const int rbase = 32 * (wv >> 1), cbase = 64 * (wv & 1);
  const int mbase = blockIdx.x * 64;
  f32x4 acc[2][4];
#pragma unroll
  for (int m = 0; m < 2; ++m)
#pragma unroll
    for (int n = 0; n < 4; ++n) acc[m][n] = (f32x4){0.f, 0.f, 0.f, 0.f};

  for (int k2 = 0; k2 < 2; ++k2) {
    if (k2) __syncthreads();
    for (int fi = t; fi < 1024; fi += 256) {
      int row = fi >> 4, c8 = fi & 15;
      *(uint4*)&As[row * 136 + c8 * 8] =
          ((const uint4*)ff)[(size_t)(mbase + row) * 32 + k2 * 16 + c8];
    }
    for (int fi = t; fi < 2048; fi += 256) {
      int row = fi >> 4, c8 = fi & 15;
      ((uint4*)&Ws[row * 136])[c8] =
          ((const uint4*)(w2B + (size_t)row * 256 + k2 * 128))[c8];
    }
    __syncthreads();
    mma_k128<2>(As, Ws, (rbase + l15) * 136 + quad * 8, 16 * 136,
                (cbase + l15) * 136 + quad * 8, acc);
  }
  __syncthreads();

  float* Yf = (float*)ldsraw;
  float* p1 = (float*)(ldsraw + 33792);
  float* p2 = (float*)(ldsraw + 34816);
  float* Ms = (float*)(ldsraw + 35840);
  float* Rs = (float*)(ldsraw + 36096);
#pragma unroll
  for (int nt = 0; nt < 4; ++nt) {
    int col = cbase + nt * 16 + l15;
    float bias = b2[col];
#pragma unroll
    for (int mt = 0; mt < 2; ++mt)
#pragma unroll
      for (int r = 0; r < 4; ++r)
        Yf[(rbase + mt * 16 + quad * 4 + r) * 132 + col] = acc[mt][nt][r] + bias;
  }
  __syncthreads();
  for (int fi = t; fi < 1024; fi += 256) {
    int row = fi >> 4, c8 = fi & 15;
    uint4 xv = ((const uint4*)hres)[(size_t)(mbase + row) * 16 + c8];
    float* yp = &Yf[row * 132 + c8 * 8];
    float a, b;
    unpack2(xv.x, a, b); yp[0] += a; yp[1] += b;
    unpack2(xv.y, a, b); yp[2] += a; yp[3] += b;
    unpack2(xv.z, a, b); yp[4] += a; yp[5] += b;
    unpack2(xv.w, a, b); yp[6] += a; yp[7] += b;
  }
  __syncthreads();
  {
    int r = t & 63, g = t >> 6;
    float s = 0.f, s2 = 0.f;
    for (int c = g * 32; c < g * 32 + 32; ++c) { float v = Yf[r * 132 + c]; s += v; s2 += v * v; }
    p1[g * 64 + r] = s; p2[g * 64 + r] = s2;
  }
  __syncthreads();
  if (t < 64) {
    float s = p1[t] + p1[64 + t] + p1[128 + t] + p1[192 + t];
    float s2 = p2[t] + p2[64 + t] + p2[128 + t] + p2[192 + t];
    float m = s * (1.f / 128.f);
    float var = s2 * (1.f / 128.f) - m * m;
    Ms[t] = m; Rs[t] = rsqrtf(var + 1e-5f);
  }
  __syncthreads();
  for (int fi = t; fi < 1024; fi += 256) {
    int row = fi >> 4, c8 = fi & 15;
    float m = Ms[row], rr = Rs[row];
    const float* yp = &Yf[row * 132 + c8 * 8];
    uint4 ov;
    float v0, v1;
#define LNPAIR(J, FLD) \
    v0 = (yp[2*J] - m) * rr * lnw[c8*8+2*J] + lnb[c8*8+2*J]; \
    v1 = (yp[2*J+1] - m) * rr * lnw[c8*8+2*J+1] + lnb[c8*8+2*J+1]; \
    ov.FLD = pack2(v0, v1);
    LNPAIR(0, x) LNPAIR(1, y) LNPAIR(2, z) LNPAIR(3, w)
#undef LNPAIR
    ((uint4*)xout)[(size_t)(mbase + row) * 16 + c8] = ov;
  }
}

// ---------------------------------------------------------------------------
__global__ void idx_init_kernel(int* __restrict__ idxmap) {
  int i = blockIdx.x * 256 + threadIdx.x;
  if (i < 2 * HWPIX) idxmap[i] = -1;
}

__global__ void scatter_kernel(const int* __restrict__ coors, int* __restrict__ idxmap) {
  int i = blockIdx.x * 256 + threadIdx.x;
  if (i >= NVOX) return;
  int b = coors[i * 4 + 0], y = coors[i * 4 + 2], xx = coors[i * 4 + 3];
  atomicMax(&idxmap[b * HWPIX + y * 320 + xx], i);
}

__global__ void canvas_kernel(const unsigned short* __restrict__ x,
                              const int* __restrict__ idxmap,
                              unsigned short* __restrict__ canvas) {
  int idx = blockIdx.x * 256 + threadIdx.x;
  if (idx >= 2 * HWPIX * 16) return;
  int cell = idx >> 4, c8 = idx & 15;
  int vox = idxmap[cell];
  uint4 v = {0u, 0u, 0u, 0u};
  if (vox >= 0) v = ((const uint4*)x)[(size_t)vox * 16 + c8];
  ((uint4*)canvas)[idx] = v;
}

// ---------------------------------------------------------------------------
// Conv 3x3 pad 1, NHWC bf16 in. Block: 64 px x 128 cout. Register prefetch of
// next tap's weights and next dy's patch row hides L2 latency under MFMAs.
template <int NCHW_OUT>
__global__ __launch_bounds__(256) void conv_kernel(
    const unsigned short* __restrict__ in, const unsigned short* __restrict__ wTb,
    void* __restrict__ outp) {
  __shared__ __align__(16) char ldsraw[52768];
  short* patch = (short*)ldsraw;           // [66 cols][136 ci]
  short* Ws = (short*)(ldsraw + 17952);    // [128 co][136 ci]
  const int t = threadIdx.x;
  const int lane = t & 63, wv = t >> 6;
  const int l15 = lane & 15, quad = lane >> 4;
  const int rbase = 32 * (wv >> 1), cbase = 64 * (wv & 1);
  const int x0 = blockIdx.x * 64;
  const int y = blockIdx.y;
  const int b = blockIdx.z;
  const unsigned short* inb = in + (size_t)b * HWPIX * 128;
  f32x4 acc[2][4];
#pragma unroll
  for (int m = 0; m < 2; ++m)
#pragma unroll
    for (int n = 0; n < 4; ++n) acc[m][n] = (f32x4){0.f, 0.f, 0.f, 0.f};

  uint4 wreg[8], preg[5];
  // prefetch tap 0 weights + dy 0 patch row
#pragma unroll
  for (int u = 0; u < 8; ++u) {
    int fi = t + 256 * u;
    wreg[u] = ((const uint4*)(wTb + (size_t)(fi >> 4) * 128))[fi & 15];
  }
  {
    int gy = y - 1;
#pragma unroll
    for (int u = 0; u < 5; ++u) {
      int fi = t + 256 * u;
      preg[u] = (uint4){0u, 0u, 0u, 0u};
      if (fi < 1056) {
        int gx = x0 + (fi >> 4) - 1;
        if (gy >= 0 && gy < 320 && gx >= 0 && gx < 320)
          preg[u] = ((const uint4*)inb)[(size_t)(gy * 320 + gx) * 16 + (fi & 15)];
      }
    }
  }
#pragma unroll
  for (int u = 0; u < 8; ++u) {
    int fi = t + 256 * u;
    *(uint4*)&Ws[(fi >> 4) * 136 + (fi & 15) * 8] = wreg[u];
  }
#pragma unroll
  for (int u = 0; u < 5; ++u) {
    int fi = t + 256 * u;
    if (fi < 1056) *(uint4*)&patch[(fi >> 4) * 136 + (fi & 15) * 8] = preg[u];
  }
  __syncthreads();

  for (int dy = 0; dy < 3; ++dy) {
    if (dy < 2) {
      int gy = y + dy;  // row for dy+1
#pragma unroll
      for (int u = 0; u < 5; ++u) {
        int fi = t + 256 * u;
        preg[u] = (uint4){0u, 0u, 0u, 0u};
        if (fi < 1056) {
          int gx = x0 + (fi >> 4) - 1;
          if (gy >= 0 && gy < 320 && gx >= 0 && gx < 320)
            preg[u] = ((const uint4*)inb)[(size_t)(gy * 320 + gx) * 16 + (fi & 15)];
        }
      }
    }
    for (int dx = 0; dx < 3; ++dx) {
      int tap = dy * 3 + dx;
      if (tap < 8) {
#pragma unroll
        for (int u = 0; u < 8; ++u) {
          int fi = t + 256 * u;
          wreg[u] = ((const uint4*)(wTb + (size_t)((tap + 1) * 128 + (fi >> 4)) * 128))[fi & 15];
        }
      }
      mma_k128<2>(patch, Ws, (rbase + l15 + dx) * 136 + quad * 8, 16 * 136,
                  (cbase + l15) * 136 + quad * 8, acc);
      __syncthreads();
      if (tap < 8) {
#pragma unroll
        for (int u = 0; u < 8; ++u) {
          int fi = t + 256 * u;
          *(uint4*)&Ws[(fi >> 4) * 136 + (fi & 15) * 8] = wreg[u];
        }
      }
      if (dx == 2 && dy < 2) {
#pragma unroll
        for (int u = 0; u < 5; ++u) {
          int fi = t + 256 * u;
          if (fi < 1056) *(uint4*)&patch[(fi >> 4) * 136 + (fi & 15) * 8] = preg[u];
        }
      }
      __syncthreads();
    }
  }
  if (NCHW_OUT) {
    float* Yf = (float*)ldsraw;  // [128 co][68 px]
#pragma unroll
    for (int nt = 0; nt < 4; ++nt) {
      int col = cbase + nt * 16 + l15;
#pragma unroll
      for (int mt = 0; mt < 2; ++mt)
#pragma unroll
        for (int r = 0; r < 4; ++r)
          Yf[col * 68 + rbase + mt * 16 + quad * 4 + r] = fmaxf(acc[mt][nt][r], 0.f);
    }
    __syncthreads();
    float* out = (float*)outp;
    for (int fi = t; fi < 2048; fi += 256) {
      int co = fi >> 4, q4 = fi & 15;
      float4 v = *(float4*)&Yf[co * 68 + q4 * 4];
      *(float4*)&out[(size_t)(b * 128 + co) * HWPIX + y * 320 + x0 + q4 * 4] = v;
    }
  } else {
    short* Ybf = (short*)ldsraw;  // [64 px][136 co]
#pragma unroll
    for (int nt = 0; nt < 4; ++nt) {
      int col = cbase + nt * 16 + l15;
#pragma unroll
      for (int mt = 0; mt < 2; ++mt)
#pragma unroll
        for (int r = 0; r < 4; ++r)
          Ybf[(rbase + mt * 16 + quad * 4 + r) * 136 + col] =
              (short)f2bf(fmaxf(acc[mt][nt][r], 0.f));
    }
    __syncthreads();
    unsigned short* out = (unsigned short*)outp;
    for (int fi = t; fi < 1024; fi += 256) {
      int row = fi >> 4, c8 = fi & 15;
      ((uint4*)out)[((size_t)b * HWPIX + y * 320 + x0 + row) * 16 + c8] =
          ((const uint4*)&Ybf[row * 136])[c8];
    }
  }
}

// ============================================================================
extern "C" void kernel_launch(void* const* d_in, const int* in_sizes, int n_in,
                              void* d_out, int out_size, void* d_ws, size_t ws_size,
                              hipStream_t stream) {
  const float* voxel_feats = (const float*)d_in[0];
  const float* pos0 = (const float*)d_in[1];
  const float* pos1 = (const float*)d_in[2];
  const float* ipw = (const float*)d_in[3];
  const float* ipb = (const float*)d_in[4];
  const float* opw = (const float*)d_in[5];
  const float* opb = (const float*)d_in[6];
  const float* l1w = (const float*)d_in[7];
  const float* l1b = (const float*)d_in[8];
  const float* l2w = (const float*)d_in[9];
  const float* l2b = (const float*)d_in[10];
  const float* n1w = (const float*)d_in[11];
  const float* n1b = (const float*)d_in[12];
  const float* n2w = (const float*)d_in[13];
  const float* n2b = (const float*)d_in[14];
  const float* convw = (const float*)d_in[15];
  const int* coors = (const int*)d_in[16];
  const int* ind0 = (const int*)d_in[17];
  const int* ind1 = (const int*)d_in[18];

  unsigned short* ws = (unsigned short*)d_ws;
  const size_t NC = (size_t)NVOX * CDIM;  // 15,360,000
  unsigned short* bx = ws;
  unsigned short* bq = ws + NC;
  unsigned short* bk = ws + 2 * NC;
  unsigned short* bv = ws + 3 * NC;
  unsigned short* bh = ws + 4 * NC;
  unsigned short* bff = ws + 5 * NC;       // 2*NC
  unsigned short* wB = ws + 7 * NC;        // bf16 weights
  unsigned short* ipwB = wB;               // 196608
  unsigned short* opwB = wB + 196608;      // 65536
  unsigned short* l1wB = wB + 262144;      // 131072
  unsigned short* l2wB = wB + 393216;      // 131072
  unsigned short* convB = wB + 524288;     // 294912
  int* idxmap = (int*)(wB + 819200);       // 204800 ints
  unsigned short* canvas = bq;             // spans bq..bk
  unsigned short* c1out = bv;              // spans bv..bh

  cvt_kernel<<<15000, 256, 0, stream>>>(voxel_feats, bx, 3840000);
  cvt_kernel<<<192, 256, 0, stream>>>(ipw, ipwB, 49152);
  cvt_kernel<<<64, 256, 0, stream>>>(opw, opwB, 16384);
  cvt_kernel<<<128, 256, 0, stream>>>(l1w, l1wB, 32768);
  cvt_kernel<<<128, 256, 0, stream>>>(l2w, l2wB, 32768);
  cvtT_kernel<<<1152, 256, 0, stream>>>(convw, convB);

  for (int l = 0; l < 4; ++l) {
    const int* ind = (l & 1) ? ind1 : ind0;
    const float* pos = (l & 1) ? pos1 : pos0;
    qkv_kernel<<<1875, 256, 0, stream>>>(
        bx, pos, ind, ipwB + (size_t)l * 49152, ipb + l * 384, bq, bk, bv);
    attn_kernel<<<NWIN, 256, 0, stream>>>(bq, bk, bv);
    outln_kernel<<<1875, 256, 0, stream>>>(
        bq, ind, opwB + (size_t)l * 16384, opb + l * 128, bx,
        n1w + l * 128, n1b + l * 128, bh);
    ffn1_kernel<<<1875, 256, 0, stream>>>(
        bh, l1wB + (size_t)l * 32768, l1b + l * 256, bff);
    ffn2_kernel<<<1875, 256, 0, stream>>>(
        bff, l2wB + (size_t)l * 32768, l2b + l * 128, bh,
        n2w + l * 128, n2b + l * 128, bx);
  }

  idx_init_kernel<<<800, 256, 0, stream>>>(idxmap);
  scatter_kernel<<<(NVOX + 255) / 256, 256, 0, stream>>>(coors, idxmap);
  canvas_kernel<<<12800, 256, 0, stream>>>(bx, idxmap, canvas);

  conv_kernel<0><<<dim3(5, 320, 2), 256, 0, stream>>>(canvas, convB, (void*)c1out);
  conv_kernel<1><<<dim3(5, 320, 2), 256, 0, stream>>>(c1out, convB + 9 * 16384, d_out);
}